// Round 3
// baseline (394.870 us; speedup 1.0000x reference)
//
#include <hip/hip_runtime.h>
#include <hip/hip_bf16.h>
#include <math.h>

// Problem constants
constexpr int Ncfg = 4096;
constexpr int Dcfg = 4096;
constexpr int Ocfg = 4096;
constexpr int Ecfg = 8;
constexpr int Rcfg = 16;
constexpr int KD   = Dcfg + Ecfg * Rcfg;   // 4224 fused-K
constexpr int NKT  = KD / 64;              // 66 K-tiles of BK=64
constexpr float ALPHA_C = 1.0f;
constexpr double TEMP_C = 1.0;

// Workspace layout (bytes)
constexpr size_t BT_OFF = 0;                                   // B'^T bf16 [O][KD]
constexpr size_t AP_OFF = BT_OFF + (size_t)Ocfg * KD * 2;      // A'   bf16 [N][KD]
constexpr size_t AT_OFF = AP_OFF + (size_t)Ncfg * KD * 2;      // lora_A^T bf16 [E][R][D]
constexpr size_t G_OFF  = AT_OFF + (size_t)Ecfg * Rcfg * Dcfg * 2; // gates f32 [N][16]

typedef short bf16x8 __attribute__((ext_vector_type(8)));
typedef float f32x4  __attribute__((ext_vector_type(4)));

__device__ __forceinline__ void async_load16(const __hip_bfloat16* g, __hip_bfloat16* l) {
  __builtin_amdgcn_global_load_lds((__attribute__((address_space(1))) void*)(g),
                                   (__attribute__((address_space(3))) void*)(l), 16, 0, 0);
}

// ---------------------------------------------------------------------------
// Launch 1: pure transposes (gates family moved to gates_lora_kernel).
//   [0,    4096): W (D,O) -> BT[o][0:4096] transpose+cast, 64x64 tiles
//   [4096, 4224): lora_B (E*R,O) -> BT[o][4096:4224]
//   [4224, 4352): lora_A (E,D,R) -> AT (E,R,D) bf16
// ---------------------------------------------------------------------------
__global__ __launch_bounds__(256) void prep_parallel_kernel(
    const float* __restrict__ W,  const float* __restrict__ lB,
    const float* __restrict__ lA,
    __hip_bfloat16* __restrict__ BT, __hip_bfloat16* __restrict__ AT) {
  __shared__ union {
    float tile[64][65];     // 64x64 transpose staging (+1 pad)
    float atile[256][17];   // loraA staging
  } sm;
  const int bid = blockIdx.x;
  const int tid = threadIdx.x;

  if (bid < 4224) {
    // ---------------- W / lora_B transpose+cast, 64x64 tile ----------------
    const float* src; int r0, c0, dstOff;
    if (bid < 4096) {          // W: id in [0,4096)
      int id = bid;
      src = W; r0 = (id & 63) * 64; c0 = (id >> 6) * 64; dstOff = 0;
    } else {                   // lB flat (128 x O): id in [0,128)
      int id = bid - 4096;
      src = lB; r0 = (id & 1) * 64; c0 = (id >> 1) * 64; dstOff = Dcfg;
    }
#pragma unroll
    for (int it = 0; it < 4; it++) {
      int flat = it * 256 + tid;
      int i = flat >> 4, f = flat & 15;
      float4 v = *(const float4*)(src + (size_t)(r0 + i) * Ocfg + c0 + 4 * f);
      sm.tile[i][4 * f + 0] = v.x;
      sm.tile[i][4 * f + 1] = v.y;
      sm.tile[i][4 * f + 2] = v.z;
      sm.tile[i][4 * f + 3] = v.w;
    }
    __syncthreads();
#pragma unroll
    for (int it = 0; it < 4; it++) {
      int flat = it * 256 + tid;
      int j = flat >> 4, q = flat & 15;
      union { ushort4 u; __hip_bfloat16 h[4]; } p;
      p.h[0] = __float2bfloat16(sm.tile[4 * q + 0][j]);
      p.h[1] = __float2bfloat16(sm.tile[4 * q + 1][j]);
      p.h[2] = __float2bfloat16(sm.tile[4 * q + 2][j]);
      p.h[3] = __float2bfloat16(sm.tile[4 * q + 3][j]);
      *(ushort4*)(BT + (size_t)(c0 + j) * KD + dstOff + r0 + 4 * q) = p.u;
    }
  } else {
    // ---------------- lora_A (E,D,R) -> AT (E,R,D) bf16 ----------------
    const int id = bid - 4224;
    const int e = id >> 4, d0 = (id & 15) * 256;
#pragma unroll
    for (int it = 0; it < 16; it++) {
      int idx = it * 256 + tid;
      int d = idx >> 4, rr = idx & 15;
      sm.atile[d][rr] = lA[((size_t)e * Dcfg + d0 + d) * Rcfg + rr];
    }
    __syncthreads();
#pragma unroll
    for (int rr = 0; rr < Rcfg; rr++) {
      AT[((size_t)e * Rcfg + rr) * Dcfg + d0 + tid] = __float2bfloat16(sm.atile[tid][rr]);
    }
  }
}

// ---------------------------------------------------------------------------
// Launch 2 (FUSED): per 16-row block, ONE pass over x computes
//   (a) 9 fp64 gate logits per row  (lane owns row m=lane&15, quad k-octet;
//       quad shfl-reduce -> LDS -> wave0's 16 lanes run top-2 softmax in
//       PARALLEL, one row per lane — replaces the old serial lane-0 loop)
//   (b) t[n,e,:] = x@lora_A[e] via MFMA (lora_t body, unchanged)
// then writes gates[], gated lora cols of Ap, and Ap base = g0*x (x rows are
// block-local -> L1/L2-hot on re-read).
// Saves a full 67 MB HBM pass of x and one kernel launch vs the old
// prep-gates + lora_t pair. fp64 sum order differs only in grouping
// (~1e-13 rel) — top-2 selection and gate values unaffected.
// ---------------------------------------------------------------------------
__global__ __launch_bounds__(512) void gates_lora_kernel(
    const float* __restrict__ x, const float* __restrict__ gw,
    const __hip_bfloat16* __restrict__ AT,
    float* __restrict__ gates, __hip_bfloat16* __restrict__ Ap) {
  const int n0 = blockIdx.x * 16;
  const int tid = threadIdx.x;
  const int wave = tid >> 6, lane = tid & 63;
  const int m = lane & 15, quad = lane >> 4;
  const int kbase = wave * 512;

  __shared__ union {
    double dsum[8][16][9];   // per-wave row logit partials (consumed early)
    f32x4  red[8][8][64];    // lora accumulator reduce (used after)
  } sm;
  __shared__ float gsm[16][16];   // per-row gates 0..8

  f32x4 acc[8] = {};
  double acc9[9];
#pragma unroll
  for (int e = 0; e < 9; e++) acc9[e] = 0.0;

  const float* xrow = x + (size_t)(n0 + m) * Dcfg + kbase + quad * 8;
  const float* gwr  = gw + kbase + quad * 8;
  const __hip_bfloat16* atb = AT + (size_t)m * Dcfg + kbase + quad * 8;

  for (int kb = 0; kb < 512; kb += 32) {
    float4 x0 = *(const float4*)(xrow + kb);
    float4 x1 = *(const float4*)(xrow + kb + 4);
    union { bf16x8 v; __hip_bfloat16 h[8]; } a;
    a.h[0] = __float2bfloat16(x0.x); a.h[1] = __float2bfloat16(x0.y);
    a.h[2] = __float2bfloat16(x0.z); a.h[3] = __float2bfloat16(x0.w);
    a.h[4] = __float2bfloat16(x1.x); a.h[5] = __float2bfloat16(x1.y);
    a.h[6] = __float2bfloat16(x1.z); a.h[7] = __float2bfloat16(x1.w);
#pragma unroll
    for (int e = 0; e < Ecfg; e++) {
      bf16x8 b = *(const bf16x8*)(atb + (size_t)e * Rcfg * Dcfg + kb);
      acc[e] = __builtin_amdgcn_mfma_f32_16x16x32_bf16(a.v, b, acc[e], 0, 0, 0);
    }
    double xd[8];
    xd[0] = (double)x0.x; xd[1] = (double)x0.y; xd[2] = (double)x0.z; xd[3] = (double)x0.w;
    xd[4] = (double)x1.x; xd[5] = (double)x1.y; xd[6] = (double)x1.z; xd[7] = (double)x1.w;
#pragma unroll
    for (int e = 0; e < 9; e++) {
      float4 g0v = *(const float4*)(gwr + (size_t)e * Dcfg + kb);       // lanes of a quad
      float4 g1v = *(const float4*)(gwr + (size_t)e * Dcfg + kb + 4);   // broadcast-coalesced
      acc9[e] += xd[0] * (double)g0v.x + xd[1] * (double)g0v.y +
                 xd[2] * (double)g0v.z + xd[3] * (double)g0v.w +
                 xd[4] * (double)g1v.x + xd[5] * (double)g1v.y +
                 xd[6] * (double)g1v.z + xd[7] * (double)g1v.w;
    }
  }
  // quad reduce: lanes {m, m+16, m+32, m+48} share row m
#pragma unroll
  for (int e = 0; e < 9; e++) {
    acc9[e] += __shfl_xor(acc9[e], 16, 64);
    acc9[e] += __shfl_xor(acc9[e], 32, 64);
  }
  if (lane < 16) {
#pragma unroll
    for (int e = 0; e < 9; e++) sm.dsum[wave][lane][e] = acc9[e];
  }
  __syncthreads();
  if (wave == 0 && lane < 16) {
    double lg[9];
#pragma unroll
    for (int e = 0; e < 9; e++) {
      double s = 0.0;
#pragma unroll
      for (int w = 0; w < 8; w++) s += sm.dsum[w][lane][e];
      lg[e] = s;
    }
    // top-2 over experts 1..8, lowest index wins ties (jax top_k)
    int i1 = 1;
    for (int e = 2; e <= 8; e++) if (lg[e] > lg[i1]) i1 = e;
    int i2 = -1; double v2 = -1e300;
    for (int e = 1; e <= 8; e++) if (e != i1 && lg[e] > v2) { v2 = lg[e]; i2 = e; }
    double vals[9];
    vals[0] = lg[0];
    for (int e = 1; e <= 8; e++) vals[e] = (e == i1 || e == i2) ? lg[e] : 0.0; // zeros, NOT -inf
    double mx = vals[0];
    for (int e = 1; e < 9; e++) mx = fmax(mx, vals[e]);
    double se = 0.0, ex[9];
    for (int e = 0; e < 9; e++) { ex[e] = exp((vals[e] - mx) / TEMP_C); se += ex[e]; }
    const int n = n0 + lane;
    for (int e = 0; e < 9; e++) {
      float gf = (float)(ex[e] / se);
      gates[n * 16 + e] = gf;
      gsm[lane][e] = gf;
    }
  }
  __syncthreads();   // gsm published; dsum dead -> red may clobber union
#pragma unroll
  for (int e = 0; e < Ecfg; e++) sm.red[wave][e][lane] = acc[e];
  __syncthreads();
  {
    const int e = wave;   // wave w -> expert w
    f32x4 s = sm.red[0][e][lane];
#pragma unroll
    for (int w = 1; w < 8; w++) s += sm.red[w][e][lane];
#pragma unroll
    for (int rg = 0; rg < 4; rg++) {
      int nn = n0 + quad * 4 + rg;
      float g = gsm[quad * 4 + rg][1 + e];
      Ap[(size_t)nn * KD + Dcfg + e * Rcfg + m] = __float2bfloat16(ALPHA_C * g * s[rg]);
    }
  }
  // ---- Ap base: wave w owns rows n0+2w, n0+2w+1 (x rows L1/L2-hot) ----
  {
    const int ra = 2 * wave, rb = 2 * wave + 1;
    const float g0A = gsm[ra][0], g0B = gsm[rb][0];
    const float4* xa4 = (const float4*)(x + (size_t)(n0 + ra) * Dcfg);
    const float4* xb4 = (const float4*)(x + (size_t)(n0 + rb) * Dcfg);
    __hip_bfloat16* ara = Ap + (size_t)(n0 + ra) * KD;
    __hip_bfloat16* arb = Ap + (size_t)(n0 + rb) * KD;
    for (int i = 0; i < 16; i++) {
      int fi = lane + 64 * i;
      float4 xa = xa4[fi], xb = xb4[fi];
      union { ushort4 u; __hip_bfloat16 h[4]; } p;
      p.h[0] = __float2bfloat16(g0A * xa.x);
      p.h[1] = __float2bfloat16(g0A * xa.y);
      p.h[2] = __float2bfloat16(g0A * xa.z);
      p.h[3] = __float2bfloat16(g0A * xa.w);
      *(ushort4*)(ara + (size_t)fi * 4) = p.u;
      p.h[0] = __float2bfloat16(g0B * xb.x);
      p.h[1] = __float2bfloat16(g0B * xb.y);
      p.h[2] = __float2bfloat16(g0B * xb.z);
      p.h[3] = __float2bfloat16(g0B * xb.w);
      *(ushort4*)(arb + (size_t)fi * 4) = p.u;
    }
  }
}

// ---------------------------------------------------------------------------
// Launch 3: GEMM  out = A'(N x KD) @ B'(KD x O) + g0[n]*bias[o]
// FROZEN from R2 (137.4 us, MfmaUtil 44.5, bank conflicts 0).
// 256x256 tile, BK=64, 8 waves (2M x 4N, 128x64 per wave), 128 KiB LDS
// double buffer, 3-bit slot swizzle, counted-vmcnt 4-phase/K-tile schedule.
// ---------------------------------------------------------------------------
#define STG(gbase, lbase, u, ktile)                                              \
  __builtin_amdgcn_global_load_lds(                                              \
      (__attribute__((address_space(1))) void*)((gbase) + (size_t)(u) * 64 * KD  \
                                                + (size_t)(ktile) * 64),         \
      (__attribute__((address_space(3))) void*)((lbase) + (u) * 8192 + dst),     \
      16, 0, 0)

__global__ __launch_bounds__(512, 2) void gemm_kernel(
    const __hip_bfloat16* __restrict__ Ap, const __hip_bfloat16* __restrict__ BT,
    const float* __restrict__ gates, const float* __restrict__ bias,
    float* __restrict__ out) {
  __shared__ char smem[131072];
  const int tid = threadIdx.x;
  const int m0 = blockIdx.y * 256, n0 = blockIdx.x * 256;
  const int wave = tid >> 6, lane = tid & 63;
  const int wm = wave >> 2, wn = wave & 3;       // 2 x 4 wave grid
  const int mr = lane & 15, quad = lane >> 4;

  // staging: per-thread pre-swizzled global source (3-bit slot involution)
  const int trow = tid >> 3;                                       // 0..63
  const int cswz = (((tid & 7) ^ ((tid >> 3) & 7)) << 3);          // bf16 elems
  const __hip_bfloat16* gA = Ap + (size_t)(m0 + trow) * KD + cswz;
  const __hip_bfloat16* gB = BT + (size_t)(n0 + trow) * KD + cswz;
  const int dst = tid << 4;

  // swizzled ds_read: col byte = (kh*64 + quad*16) ^ rswz, rswz = (mr&7)<<4
  const int rswz = (mr & 7) << 4;
  const int arow = (wm * 128 + mr) * 128;
  const int brow = (wn * 64 + mr) * 128;

  f32x4 acc[8][4] = {};

  // ---- prologue: K0 all 4 half-tiles (8 issues) + K1 first 3 (6 issues) ----
  STG(gA, smem,          0, 0); STG(gA, smem,          1, 0);
  STG(gA, smem,          2, 0); STG(gA, smem,          3, 0);
  STG(gB, smem + 32768,  0, 0); STG(gB, smem + 32768,  1, 0);
  STG(gB, smem + 32768,  2, 0); STG(gB, smem + 32768,  3, 0);
  STG(gA, smem + 65536,  0, 1); STG(gA, smem + 65536,  1, 1);
  STG(gA, smem + 65536,  2, 1); STG(gA, smem + 65536,  3, 1);
  STG(gB, smem + 98304,  0, 1); STG(gB, smem + 98304,  1, 1);
  asm volatile("s_waitcnt vmcnt(6)" ::: "memory");
  __builtin_amdgcn_s_barrier();

  for (int kt = 0; kt < NKT; ++kt) {
    const bool odd = kt & 1;
    const char* At = odd ? (smem + 65536) : smem;            // compute buf
    const char* Bt = odd ? (smem + 98304) : (smem + 32768);
    char* An = odd ? smem : (smem + 65536);                  // next buf
    char* Bn = odd ? (smem + 32768) : (smem + 98304);

    bf16x8 a[4][2], b0r[2][2], b1r[2][2];

    // ---------------- phase 1 ----------------
#pragma unroll
    for (int i = 0; i < 4; ++i)
#pragma unroll
      for (int kh = 0; kh < 2; ++kh)
        a[i][kh] = *(const bf16x8*)(At + arow + i * 2048 + ((kh * 64 + quad * 16) ^ rswz));
#pragma unroll
    for (int j = 0; j < 2; ++j)
#pragma unroll
      for (int kh = 0; kh < 2; ++kh)
        b0r[j][kh] = *(const bf16x8*)(Bt + brow + j * 2048 + ((kh * 64 + quad * 16) ^ rswz));
    if (kt + 1 < NKT) { STG(gB, Bn, 2, kt + 1); STG(gB, Bn, 3, kt + 1); }
    __builtin_amdgcn_s_barrier();
    asm volatile("s_waitcnt lgkmcnt(0)" ::: "memory");
    __builtin_amdgcn_s_setprio(1);
#pragma unroll
    for (int i = 0; i < 4; ++i)
#pragma unroll
      for (int j = 0; j < 2; ++j)
#pragma unroll
        for (int kh = 0; kh < 2; ++kh)
          acc[i][j] = __builtin_amdgcn_mfma_f32_16x16x32_bf16(a[i][kh], b0r[j][kh], acc[i][j], 0, 0, 0);
    __builtin_amdgcn_s_setprio(0);
    __builtin_amdgcn_s_barrier();

    // ---------------- phase 2 ----------------
#pragma unroll
    for (int j = 0; j < 2; ++j)
#pragma unroll
      for (int kh = 0; kh < 2; ++kh)
        b1r[j][kh] = *(const bf16x8*)(Bt + brow + (2 + j) * 2048 + ((kh * 64 + quad * 16) ^ rswz));
    __builtin_amdgcn_s_barrier();
    asm volatile("s_waitcnt lgkmcnt(0)" ::: "memory");
    __builtin_amdgcn_s_setprio(1);
#pragma unroll
    for (int i = 0; i < 4; ++i)
#pragma unroll
      for (int j = 0; j < 2; ++j)
#pragma unroll
        for (int kh = 0; kh < 2; ++kh)
          acc[i][2 + j] = __builtin_amdgcn_mfma_f32_16x16x32_bf16(a[i][kh], b1r[j][kh], acc[i][2 + j], 0, 0, 0);
    __builtin_amdgcn_s_setprio(0);
    __builtin_amdgcn_s_barrier();

    // ---------------- phase 3 ----------------
#pragma unroll
    for (int i = 0; i < 4; ++i)
#pragma unroll
      for (int kh = 0; kh < 2; ++kh)
        a[i][kh] = *(const bf16x8*)(At + arow + (4 + i) * 2048 + ((kh * 64 + quad * 16) ^ rswz));
    __builtin_amdgcn_s_barrier();
    asm volatile("s_waitcnt lgkmcnt(0)" ::: "memory");
    __builtin_amdgcn_s_setprio(1);
#pragma unroll
    for (int i = 0; i < 4; ++i)
#pragma unroll
      for (int j = 0; j < 2; ++j)
#pragma unroll
        for (int kh = 0; kh < 2; ++kh)
          acc[4 + i][2 + j] = __builtin_amdgcn_mfma_f32_16x16x32_bf16(a[i][kh], b1r[j][kh], acc[4 + i][2 + j], 0, 0, 0);
    __builtin_amdgcn_s_setprio(0);
    __builtin_amdgcn_s_barrier();

    // ---------------- phase 4 (reg-only MFMA; stage K_{kt+2} into buf c) ----
    if (kt + 2 < NKT) {
      char* Ac = (char*)At; char* Bc = (char*)Bt;
      STG(gA, Ac, 0, kt + 2); STG(gA, Ac, 1, kt + 2);
      STG(gA, Ac, 2, kt + 2); STG(gA, Ac, 3, kt + 2);
      STG(gB, Bc, 0, kt + 2); STG(gB, Bc, 1, kt + 2);
    }
    __builtin_amdgcn_s_setprio(1);
#pragma unroll
    for (int i = 0; i < 4; ++i)
#pragma unroll
      for (int j = 0; j < 2; ++j)
#pragma unroll
        for (int kh = 0; kh < 2; ++kh)
          acc[4 + i][j] = __builtin_amdgcn_mfma_f32_16x16x32_bf16(a[i][kh], b0r[j][kh], acc[4 + i][j], 0, 0, 0);
    __builtin_amdgcn_s_setprio(0);
    if (kt + 2 < NKT) {
      asm volatile("s_waitcnt vmcnt(6)" ::: "memory");
    } else if (kt + 1 < NKT) {
      asm volatile("s_waitcnt vmcnt(0)" ::: "memory");
    }
    if (kt + 1 < NKT) __builtin_amdgcn_s_barrier();
  }

  // ---------------- epilogue ----------------
  float bv[4];
#pragma unroll
  for (int j = 0; j < 4; ++j) bv[j] = bias[n0 + wn * 64 + j * 16 + mr];
#pragma unroll
  for (int i = 0; i < 8; ++i) {
    const int rowb = m0 + wm * 128 + i * 16 + quad * 4;
#pragma unroll
    for (int rg = 0; rg < 4; ++rg) {
      const int row = rowb + rg;
      const float g0 = gates[row * 16];
      float* orow = out + (size_t)row * Ocfg + n0 + wn * 64 + mr;
#pragma unroll
      for (int j = 0; j < 4; ++j)
        orow[j * 16] = acc[i][j][rg] + g0 * bv[j];
    }
  }
}

// ---------------------------------------------------------------------------
extern "C" void kernel_launch(void* const* d_in, const int* in_sizes, int n_in,
                              void* d_out, int out_size, void* d_ws, size_t ws_size,
                              hipStream_t stream) {
  const float* x  = (const float*)d_in[0];
  const float* W  = (const float*)d_in[1];   // (D, O)
  const float* b  = (const float*)d_in[2];   // (O,)
  const float* lA = (const float*)d_in[3];   // (E, D, R)
  const float* lB = (const float*)d_in[4];   // (E, R, O)
  const float* gw = (const float*)d_in[5];   // (E+1, D)
  // d_in[6] = bvv, unused by the reference
  float* out = (float*)d_out;

  char* ws = (char*)d_ws;
  __hip_bfloat16* BT    = (__hip_bfloat16*)(ws + BT_OFF);
  __hip_bfloat16* Ap    = (__hip_bfloat16*)(ws + AP_OFF);
  __hip_bfloat16* AT    = (__hip_bfloat16*)(ws + AT_OFF);
  float*          gates = (float*)(ws + G_OFF);

  prep_parallel_kernel<<<dim3(4352), 256, 0, stream>>>(W, lB, lA, BT, AT);
  gates_lora_kernel<<<dim3(Ncfg / 16), 512, 0, stream>>>(x, gw, AT, gates, Ap);
  gemm_kernel<<<dim3(Ocfg / 256, Ncfg / 256), 512, 0, stream>>>(Ap, BT, gates, b, out);
}

// Round 4
// 343.243 us; speedup vs baseline: 1.1504x; 1.1504x over previous
//
#include <hip/hip_runtime.h>
#include <hip/hip_bf16.h>
#include <math.h>

// Problem constants
constexpr int Ncfg = 4096;
constexpr int Dcfg = 4096;
constexpr int Ocfg = 4096;
constexpr int Ecfg = 8;
constexpr int Rcfg = 16;
constexpr int KD   = Dcfg + Ecfg * Rcfg;   // 4224 fused-K
constexpr int NKT  = KD / 64;              // 66 K-tiles of BK=64
constexpr float ALPHA_C = 1.0f;
constexpr double TEMP_C = 1.0;

// Workspace layout (bytes)
constexpr size_t BT_OFF = 0;                                   // B'^T bf16 [O][KD]
constexpr size_t AP_OFF = BT_OFF + (size_t)Ocfg * KD * 2;      // A'   bf16 [N][KD]
constexpr size_t AT_OFF = AP_OFF + (size_t)Ncfg * KD * 2;      // lora_A^T bf16 [E][R][D]
constexpr size_t G_OFF  = AT_OFF + (size_t)Ecfg * Rcfg * Dcfg * 2; // gates f32 [N][16]

typedef short bf16x8 __attribute__((ext_vector_type(8)));
typedef float f32x4  __attribute__((ext_vector_type(4)));

__device__ __forceinline__ void async_load16(const __hip_bfloat16* g, __hip_bfloat16* l) {
  __builtin_amdgcn_global_load_lds((__attribute__((address_space(1))) void*)(g),
                                   (__attribute__((address_space(3))) void*)(l), 16, 0, 0);
}

// ---------------------------------------------------------------------------
// Launch 1: four MUTUALLY INDEPENDENT families in one wide kernel.
// REVERTED to the R2-verified version. R3's fusion of the gates family into
// the 256-block lora kernel cost +48 us: the gates (VALU/latency) family
// co-resident with the transpose (memory) family here is real concurrency.
//   [0,    512): gates + base-scale — 8 rows/block, 2 rows/wave.
//   [512, 4608): W (D,O) -> BT[o][0:4096] transpose+cast, 64x64 tiles
//   [4608,4736): lora_B (E*R,O) -> BT[o][4096:4224]
//   [4736,4864): lora_A (E,D,R) -> AT (E,R,D) bf16
// ---------------------------------------------------------------------------
__global__ __launch_bounds__(256) void prep_parallel_kernel(
    const float* __restrict__ x,  const float* __restrict__ gw,
    const float* __restrict__ W,  const float* __restrict__ lB,
    const float* __restrict__ lA,
    float* __restrict__ gates, __hip_bfloat16* __restrict__ Ap,
    __hip_bfloat16* __restrict__ BT, __hip_bfloat16* __restrict__ AT) {
  __shared__ union {
    float tile[64][65];     // 64x64 transpose staging (+1 pad)
    float atile[256][17];   // loraA staging
  } sm;
  const int bid = blockIdx.x;
  const int tid = threadIdx.x;

  if (bid < 512) {
    // ---------------- gates + base-scale ----------------
    const int wave = tid >> 6, lane = tid & 63;
    const int na = bid * 8 + wave * 2, nb = na + 1;   // 2 rows per wave
    const float4* xa4 = (const float4*)(x + (size_t)na * Dcfg);
    const float4* xb4 = (const float4*)(x + (size_t)nb * Dcfg);
    const float4* gw4 = (const float4*)gw;
    double accA[9], accB[9];
#pragma unroll
    for (int e = 0; e < 9; e++) { accA[e] = 0.0; accB[e] = 0.0; }
    for (int i = 0; i < 16; i++) {
      int fi = lane + 64 * i;
      float4 xa = xa4[fi], xb = xb4[fi];
#pragma unroll
      for (int e = 0; e < 9; e++) {
        float4 w = gw4[e * 1024 + fi];   // shared load serves both rows
        accA[e] += (double)xa.x * (double)w.x + (double)xa.y * (double)w.y +
                   (double)xa.z * (double)w.z + (double)xa.w * (double)w.w;
        accB[e] += (double)xb.x * (double)w.x + (double)xb.y * (double)w.y +
                   (double)xb.z * (double)w.z + (double)xb.w * (double)w.w;
      }
    }
#pragma unroll
    for (int off = 32; off >= 1; off >>= 1) {
#pragma unroll
      for (int e = 0; e < 9; e++) {
        accA[e] += __shfl_xor(accA[e], off, 64);
        accB[e] += __shfl_xor(accB[e], off, 64);
      }
    }
    float g0A_l = 0.f, g0B_l = 0.f;
    if (lane == 0) {
#pragma unroll
      for (int r = 0; r < 2; r++) {
        double lg[9];
#pragma unroll
        for (int e = 0; e < 9; e++) lg[e] = r ? accB[e] : accA[e];
        // top-2 over experts 1..8, lowest index wins ties (jax top_k)
        int i1 = 1;
        for (int e = 2; e <= 8; e++) if (lg[e] > lg[i1]) i1 = e;
        int i2 = -1; double v2 = -1e300;
        for (int e = 1; e <= 8; e++) if (e != i1 && lg[e] > v2) { v2 = lg[e]; i2 = e; }
        double vals[9];
        vals[0] = lg[0];
        for (int e = 1; e <= 8; e++) vals[e] = (e == i1 || e == i2) ? lg[e] : 0.0; // zeros, NOT -inf
        double mx = vals[0];
        for (int e = 1; e < 9; e++) mx = fmax(mx, vals[e]);
        double se = 0.0, ex[9];
        for (int e = 0; e < 9; e++) { ex[e] = exp((vals[e] - mx) / TEMP_C); se += ex[e]; }
        const int n = r ? nb : na;
        for (int e = 0; e < 9; e++) gates[n * 16 + e] = (float)(ex[e] / se);
        if (r == 0) g0A_l = (float)(ex[0] / se); else g0B_l = (float)(ex[0] / se);
      }
    }
    const float g0A = __shfl(g0A_l, 0, 64);
    const float g0B = __shfl(g0B_l, 0, 64);
    // Phase B: base-scale writes (x rows are L2-hot from phase A)
    __hip_bfloat16* ara = Ap + (size_t)na * KD;
    __hip_bfloat16* arb = Ap + (size_t)nb * KD;
    for (int i = 0; i < 16; i++) {
      int fi = lane + 64 * i;
      float4 xa = xa4[fi], xb = xb4[fi];
      union { ushort4 u; __hip_bfloat16 h[4]; } p;
      p.h[0] = __float2bfloat16(g0A * xa.x);
      p.h[1] = __float2bfloat16(g0A * xa.y);
      p.h[2] = __float2bfloat16(g0A * xa.z);
      p.h[3] = __float2bfloat16(g0A * xa.w);
      *(ushort4*)(ara + (size_t)fi * 4) = p.u;
      p.h[0] = __float2bfloat16(g0B * xb.x);
      p.h[1] = __float2bfloat16(g0B * xb.y);
      p.h[2] = __float2bfloat16(g0B * xb.z);
      p.h[3] = __float2bfloat16(g0B * xb.w);
      *(ushort4*)(arb + (size_t)fi * 4) = p.u;
    }
  } else if (bid < 4736) {
    // ---------------- W / lora_B transpose+cast, 64x64 tile ----------------
    const float* src; int r0, c0, dstOff;
    if (bid < 4608) {          // W: id in [0,4096)
      int id = bid - 512;
      src = W; r0 = (id & 63) * 64; c0 = (id >> 6) * 64; dstOff = 0;
    } else {                   // lB flat (128 x O): id in [0,128)
      int id = bid - 4608;
      src = lB; r0 = (id & 1) * 64; c0 = (id >> 1) * 64; dstOff = Dcfg;
    }
#pragma unroll
    for (int it = 0; it < 4; it++) {
      int flat = it * 256 + tid;
      int i = flat >> 4, f = flat & 15;
      float4 v = *(const float4*)(src + (size_t)(r0 + i) * Ocfg + c0 + 4 * f);
      sm.tile[i][4 * f + 0] = v.x;
      sm.tile[i][4 * f + 1] = v.y;
      sm.tile[i][4 * f + 2] = v.z;
      sm.tile[i][4 * f + 3] = v.w;
    }
    __syncthreads();
#pragma unroll
    for (int it = 0; it < 4; it++) {
      int flat = it * 256 + tid;
      int j = flat >> 4, q = flat & 15;
      union { ushort4 u; __hip_bfloat16 h[4]; } p;
      p.h[0] = __float2bfloat16(sm.tile[4 * q + 0][j]);
      p.h[1] = __float2bfloat16(sm.tile[4 * q + 1][j]);
      p.h[2] = __float2bfloat16(sm.tile[4 * q + 2][j]);
      p.h[3] = __float2bfloat16(sm.tile[4 * q + 3][j]);
      *(ushort4*)(BT + (size_t)(c0 + j) * KD + dstOff + r0 + 4 * q) = p.u;
    }
  } else {
    // ---------------- lora_A (E,D,R) -> AT (E,R,D) bf16 ----------------
    const int id = bid - 4736;
    const int e = id >> 4, d0 = (id & 15) * 256;
#pragma unroll
    for (int it = 0; it < 16; it++) {
      int idx = it * 256 + tid;
      int d = idx >> 4, rr = idx & 15;
      sm.atile[d][rr] = lA[((size_t)e * Dcfg + d0 + d) * Rcfg + rr];
    }
    __syncthreads();
#pragma unroll
    for (int rr = 0; rr < Rcfg; rr++) {
      AT[((size_t)e * Rcfg + rr) * Dcfg + d0 + tid] = __float2bfloat16(sm.atile[tid][rr]);
    }
  }
}

// ---------------------------------------------------------------------------
// Launch 2: t[n,e,:] = x[n,:] @ lora_A[e] via 16x16x32 bf16 MFMA.
//   REVERTED to R2-verified version.
// ---------------------------------------------------------------------------
__global__ __launch_bounds__(512) void lora_t_kernel(
    const float* __restrict__ x, const __hip_bfloat16* __restrict__ AT,
    const float* __restrict__ gates, __hip_bfloat16* __restrict__ Ap) {
  const int n0 = blockIdx.x * 16;
  const int tid = threadIdx.x;
  const int wave = tid >> 6, lane = tid & 63;
  const int m = lane & 15, quad = lane >> 4;
  const int kbase = wave * 512;

  f32x4 acc[8] = {};
  const float* xrow = x + (size_t)(n0 + m) * Dcfg + kbase + quad * 8;
  const __hip_bfloat16* atb = AT + (size_t)m * Dcfg + kbase + quad * 8;
#pragma unroll 2
  for (int kb = 0; kb < 512; kb += 32) {
    float4 x0 = *(const float4*)(xrow + kb);
    float4 x1 = *(const float4*)(xrow + kb + 4);
    union { bf16x8 v; __hip_bfloat16 h[8]; } a;
    a.h[0] = __float2bfloat16(x0.x); a.h[1] = __float2bfloat16(x0.y);
    a.h[2] = __float2bfloat16(x0.z); a.h[3] = __float2bfloat16(x0.w);
    a.h[4] = __float2bfloat16(x1.x); a.h[5] = __float2bfloat16(x1.y);
    a.h[6] = __float2bfloat16(x1.z); a.h[7] = __float2bfloat16(x1.w);
#pragma unroll
    for (int e = 0; e < Ecfg; e++) {
      bf16x8 b = *(const bf16x8*)(atb + (size_t)e * Rcfg * Dcfg + kb);
      acc[e] = __builtin_amdgcn_mfma_f32_16x16x32_bf16(a.v, b, acc[e], 0, 0, 0);
    }
  }
  __shared__ f32x4 red[8][8][64];
#pragma unroll
  for (int e = 0; e < Ecfg; e++) red[wave][e][lane] = acc[e];
  __syncthreads();
  {
    const int e = wave;   // wave w -> expert w
    f32x4 s = red[0][e][lane];
#pragma unroll
    for (int w = 1; w < 8; w++) s += red[w][e][lane];
#pragma unroll
    for (int rg = 0; rg < 4; rg++) {
      int nn = n0 + quad * 4 + rg;
      float g = gates[nn * 16 + 1 + e];
      Ap[(size_t)nn * KD + Dcfg + e * Rcfg + m] = __float2bfloat16(ALPHA_C * g * s[rg]);
    }
  }
}

// ---------------------------------------------------------------------------
// Launch 3: GEMM  out = A'(N x KD) @ B'(KD x O) + g0[n]*bias[o]
// 256x256 tile, BK=64, 8 waves (2M x 4N, 128x64 per wave), 128 KiB LDS
// double buffer, 3-bit slot swizzle (R2: conflicts -> 0), counted-vmcnt
// 4-phase/K-tile schedule.
//
// R4 CHANGE: drop the per-phase explicit `s_waitcnt lgkmcnt(0)` full drain
// (ph1/ph2/ph3 pre-MFMA). The ds_reads are plain C++ loads, so the compiler
// emits PRECISE per-use lgkmcnt(N) — MFMA starts while later reads are still
// in the LDS pipe (intra-wave LDS||MFMA overlap the full drain forbade).
// Structural waits kept:
//   - ph3 END: explicit lgkmcnt(0) before closing barrier (guarantees all
//     buf-c reads retired before any wave's ph4 staging overwrites buf-c).
//     Free if reads were already drained by MFMA consumption.
//   - ph4: vmcnt(6)+barrier (staging-complete-before-read), unchanged.
// asm(""::: "memory") compiler-only fences before each closing barrier pin
// memory ops within their phase (no codegen cost).
// MFMA accumulation order unchanged -> output bit-identical (absmax must
// stay 0.03125; any change = race -> revert this wait scheme).
// ---------------------------------------------------------------------------
#define STG(gbase, lbase, u, ktile)                                              \
  __builtin_amdgcn_global_load_lds(                                              \
      (__attribute__((address_space(1))) void*)((gbase) + (size_t)(u) * 64 * KD  \
                                                + (size_t)(ktile) * 64),         \
      (__attribute__((address_space(3))) void*)((lbase) + (u) * 8192 + dst),     \
      16, 0, 0)

__global__ __launch_bounds__(512, 2) void gemm_kernel(
    const __hip_bfloat16* __restrict__ Ap, const __hip_bfloat16* __restrict__ BT,
    const float* __restrict__ gates, const float* __restrict__ bias,
    float* __restrict__ out) {
  __shared__ char smem[131072];
  const int tid = threadIdx.x;
  const int m0 = blockIdx.y * 256, n0 = blockIdx.x * 256;
  const int wave = tid >> 6, lane = tid & 63;
  const int wm = wave >> 2, wn = wave & 3;       // 2 x 4 wave grid
  const int mr = lane & 15, quad = lane >> 4;

  // staging: per-thread pre-swizzled global source (3-bit slot involution)
  const int trow = tid >> 3;                                       // 0..63
  const int cswz = (((tid & 7) ^ ((tid >> 3) & 7)) << 3);          // bf16 elems
  const __hip_bfloat16* gA = Ap + (size_t)(m0 + trow) * KD + cswz;
  const __hip_bfloat16* gB = BT + (size_t)(n0 + trow) * KD + cswz;
  const int dst = tid << 4;

  // swizzled ds_read: col byte = (kh*64 + quad*16) ^ rswz, rswz = (mr&7)<<4
  const int rswz = (mr & 7) << 4;
  const int arow = (wm * 128 + mr) * 128;
  const int brow = (wn * 64 + mr) * 128;

  f32x4 acc[8][4] = {};

  // ---- prologue: K0 all 4 half-tiles (8 issues) + K1 first 3 (6 issues) ----
  STG(gA, smem,          0, 0); STG(gA, smem,          1, 0);
  STG(gA, smem,          2, 0); STG(gA, smem,          3, 0);
  STG(gB, smem + 32768,  0, 0); STG(gB, smem + 32768,  1, 0);
  STG(gB, smem + 32768,  2, 0); STG(gB, smem + 32768,  3, 0);
  STG(gA, smem + 65536,  0, 1); STG(gA, smem + 65536,  1, 1);
  STG(gA, smem + 65536,  2, 1); STG(gA, smem + 65536,  3, 1);
  STG(gB, smem + 98304,  0, 1); STG(gB, smem + 98304,  1, 1);
  asm volatile("s_waitcnt vmcnt(6)" ::: "memory");
  __builtin_amdgcn_s_barrier();

  for (int kt = 0; kt < NKT; ++kt) {
    const bool odd = kt & 1;
    const char* At = odd ? (smem + 65536) : smem;            // compute buf
    const char* Bt = odd ? (smem + 98304) : (smem + 32768);
    char* An = odd ? smem : (smem + 65536);                  // next buf
    char* Bn = odd ? (smem + 32768) : (smem + 98304);

    bf16x8 a[4][2], b0r[2][2], b1r[2][2];

    // ---------------- phase 1 ----------------
#pragma unroll
    for (int i = 0; i < 4; ++i)
#pragma unroll
      for (int kh = 0; kh < 2; ++kh)
        a[i][kh] = *(const bf16x8*)(At + arow + i * 2048 + ((kh * 64 + quad * 16) ^ rswz));
#pragma unroll
    for (int j = 0; j < 2; ++j)
#pragma unroll
      for (int kh = 0; kh < 2; ++kh)
        b0r[j][kh] = *(const bf16x8*)(Bt + brow + j * 2048 + ((kh * 64 + quad * 16) ^ rswz));
    if (kt + 1 < NKT) { STG(gB, Bn, 2, kt + 1); STG(gB, Bn, 3, kt + 1); }
    asm volatile("" ::: "memory");
    __builtin_amdgcn_s_barrier();
    __builtin_amdgcn_s_setprio(1);
#pragma unroll
    for (int i = 0; i < 4; ++i)
#pragma unroll
      for (int j = 0; j < 2; ++j)
#pragma unroll
        for (int kh = 0; kh < 2; ++kh)
          acc[i][j] = __builtin_amdgcn_mfma_f32_16x16x32_bf16(a[i][kh], b0r[j][kh], acc[i][j], 0, 0, 0);
    __builtin_amdgcn_s_setprio(0);
    asm volatile("" ::: "memory");
    __builtin_amdgcn_s_barrier();

    // ---------------- phase 2 ----------------
#pragma unroll
    for (int j = 0; j < 2; ++j)
#pragma unroll
      for (int kh = 0; kh < 2; ++kh)
        b1r[j][kh] = *(const bf16x8*)(Bt + brow + (2 + j) * 2048 + ((kh * 64 + quad * 16) ^ rswz));
    asm volatile("" ::: "memory");
    __builtin_amdgcn_s_barrier();
    __builtin_amdgcn_s_setprio(1);
#pragma unroll
    for (int i = 0; i < 4; ++i)
#pragma unroll
      for (int j = 0; j < 2; ++j)
#pragma unroll
        for (int kh = 0; kh < 2; ++kh)
          acc[i][2 + j] = __builtin_amdgcn_mfma_f32_16x16x32_bf16(a[i][kh], b1r[j][kh], acc[i][2 + j], 0, 0, 0);
    __builtin_amdgcn_s_setprio(0);
    asm volatile("" ::: "memory");
    __builtin_amdgcn_s_barrier();

    // ---------------- phase 3 ----------------
#pragma unroll
    for (int i = 0; i < 4; ++i)
#pragma unroll
      for (int kh = 0; kh < 2; ++kh)
        a[i][kh] = *(const bf16x8*)(At + arow + (4 + i) * 2048 + ((kh * 64 + quad * 16) ^ rswz));
    asm volatile("" ::: "memory");
    __builtin_amdgcn_s_barrier();
    __builtin_amdgcn_s_setprio(1);
#pragma unroll
    for (int i = 0; i < 4; ++i)
#pragma unroll
      for (int j = 0; j < 2; ++j)
#pragma unroll
        for (int kh = 0; kh < 2; ++kh)
          acc[4 + i][2 + j] = __builtin_amdgcn_mfma_f32_16x16x32_bf16(a[i][kh], b1r[j][kh], acc[4 + i][2 + j], 0, 0, 0);
    __builtin_amdgcn_s_setprio(0);
    // STRUCTURAL: all buf-c ds_reads must retire before ph4 staging overwrites
    asm volatile("s_waitcnt lgkmcnt(0)" ::: "memory");
    __builtin_amdgcn_s_barrier();

    // ---------------- phase 4 (reg-only MFMA; stage K_{kt+2} into buf c) ----
    if (kt + 2 < NKT) {
      char* Ac = (char*)At; char* Bc = (char*)Bt;
      STG(gA, Ac, 0, kt + 2); STG(gA, Ac, 1, kt + 2);
      STG(gA, Ac, 2, kt + 2); STG(gA, Ac, 3, kt + 2);
      STG(gB, Bc, 0, kt + 2); STG(gB, Bc, 1, kt + 2);
    }
    __builtin_amdgcn_s_setprio(1);
#pragma unroll
    for (int i = 0; i < 4; ++i)
#pragma unroll
      for (int j = 0; j < 2; ++j)
#pragma unroll
        for (int kh = 0; kh < 2; ++kh)
          acc[4 + i][j] = __builtin_amdgcn_mfma_f32_16x16x32_bf16(a[i][kh], b0r[j][kh], acc[4 + i][j], 0, 0, 0);
    __builtin_amdgcn_s_setprio(0);
    if (kt + 2 < NKT) {
      asm volatile("s_waitcnt vmcnt(6)" ::: "memory");
    } else if (kt + 1 < NKT) {
      asm volatile("s_waitcnt vmcnt(0)" ::: "memory");
    }
    if (kt + 1 < NKT) __builtin_amdgcn_s_barrier();
  }

  // ---------------- epilogue ----------------
  float bv[4];
#pragma unroll
  for (int j = 0; j < 4; ++j) bv[j] = bias[n0 + wn * 64 + j * 16 + mr];
#pragma unroll
  for (int i = 0; i < 8; ++i) {
    const int rowb = m0 + wm * 128 + i * 16 + quad * 4;
#pragma unroll
    for (int rg = 0; rg < 4; ++rg) {
      const int row = rowb + rg;
      const float g0 = gates[row * 16];
      float* orow = out + (size_t)row * Ocfg + n0 + wn * 64 + mr;
#pragma unroll
      for (int j = 0; j < 4; ++j)
        orow[j * 16] = acc[i][j][rg] + g0 * bv[j];
    }
  }
}

// ---------------------------------------------------------------------------
extern "C" void kernel_launch(void* const* d_in, const int* in_sizes, int n_in,
                              void* d_out, int out_size, void* d_ws, size_t ws_size,
                              hipStream_t stream) {
  const float* x  = (const float*)d_in[0];
  const float* W  = (const float*)d_in[1];   // (D, O)
  const float* b  = (const float*)d_in[2];   // (O,)
  const float* lA = (const float*)d_in[3];   // (E, D, R)
  const float* lB = (const float*)d_in[4];   // (E, R, O)
  const float* gw = (const float*)d_in[5];   // (E+1, D)
  // d_in[6] = bvv, unused by the reference
  float* out = (float*)d_out;

  char* ws = (char*)d_ws;
  __hip_bfloat16* BT    = (__hip_bfloat16*)(ws + BT_OFF);
  __hip_bfloat16* Ap    = (__hip_bfloat16*)(ws + AP_OFF);
  __hip_bfloat16* AT    = (__hip_bfloat16*)(ws + AT_OFF);
  float*          gates = (float*)(ws + G_OFF);

  prep_parallel_kernel<<<dim3(4864), 256, 0, stream>>>(x, gw, W, lB, lA, gates, Ap, BT, AT);
  lora_t_kernel<<<dim3(Ncfg / 16), 512, 0, stream>>>(x, AT, gates, Ap);
  gemm_kernel<<<dim3(Ocfg / 256, Ncfg / 256), 512, 0, stream>>>(Ap, BT, gates, b, out);
}